// Round 15
// baseline (981.313 us; speedup 1.0000x reference)
//
#include <hip/hip_runtime.h>
#include <cstdint>
#include <cstddef>

// [B,H,N,Dh] = [4,16,2048,64]; out[b,h,m,d] = (sum_n softmax(QK^T)[n,m]) * v[b,h,m,d]
#define B_    4
#define H_    16
#define N_    2048
#define D_    64
#define BH_   (B_*H_)
#define SCALE 0.125f
#define QSCL  0.18033688011f      // SCALE * log2(e)

#define PNL   128                 // fixed panel (rows pass1 / cols pass2) per wg
#define TILEB 16384               // 128 rows of bf16[64] = 16 KB
#define BHB   (16*TILEB)          // 256 KB per (bh, tensor)
#define QKB   ((size_t)2*BH_*BHB) // 32 MB image
#define NGC   64                  // fragment-groups per chunk (half image)
#define NZW   (BH_*N_)            // 131072 floats (Z / CS / RI each)

typedef __attribute__((ext_vector_type(8))) short bf16x8;
typedef __attribute__((ext_vector_type(4))) float f32x4;

#if __has_builtin(__builtin_amdgcn_exp2f)
#define EXP2(x) __builtin_amdgcn_exp2f(x)
#else
#define EXP2(x) exp2f(x)
#endif

__device__ __forceinline__ short f2bf(float f) {
    union { float f; unsigned u; } x; x.f = f;
    unsigned r = x.u + 0x7FFF + ((x.u >> 16) & 1);  // RNE
    return (short)(r >> 16);
}

// Fragment-major byte offset of chunk (row, cc) in a (bh,tensor) image:
// tile = row>>7; group g=(row>>4)&7 (2 KB); frag f=cc>>2 (1 KB);
// lane l=(cc&3)*16+(row&15) at l*16. Streamed reads are base + l*16; image is
// 128 sequential 2 KB fragment-groups -> fully coalesced, no LDS needed.
__device__ __forceinline__ size_t fmaj(int row, int cc) {
    return ((size_t)(row >> 7) * TILEB) + (((row >> 4) & 7) << 11)
         + ((cc >> 2) << 10) + ((cc & 3) << 8) + ((row & 15) << 4);
}

// ---------------------------------------------------------------------------
// Pre-pass: build fragment-major bf16 image AND zero Z | CS | TK accumulators.
// ---------------------------------------------------------------------------
__global__ __launch_bounds__(512)
void mha_convert(const float* __restrict__ q, const float* __restrict__ k,
                 char* __restrict__ qk)
{
    const int gid = blockIdx.x * 512 + threadIdx.x;     // 2,097,152 threads
    if (gid < 2 * NZW + 4096)                           // zero Z + CS + TK
        ((int*)(qk + QKB))[gid] = 0;
    const int half = BH_ * N_ * 8;
    const bool isq = gid < half;
    const float* src = isq ? q : k;
    const float scl = isq ? QSCL : 1.0f;
    char* dst = qk + (isq ? 0 : (size_t)BH_ * BHB);
    const int id = isq ? gid : gid - half;
    const int bh  = id >> 14;
    const int row = (id >> 3) & 2047;
    const int cc  = id & 7;
    const float* p = src + ((size_t)bh * N_ + row) * D_ + cc * 8;
    float4 a = *(const float4*)p;
    float4 b = *(const float4*)(p + 4);
    bf16x8 o;
    o[0] = f2bf(a.x * scl); o[1] = f2bf(a.y * scl);
    o[2] = f2bf(a.z * scl); o[3] = f2bf(a.w * scl);
    o[4] = f2bf(b.x * scl); o[5] = f2bf(b.y * scl);
    o[6] = f2bf(b.z * scl); o[7] = f2bf(b.w * scl);
    *(bf16x8*)(dst + (size_t)bh * BHB + fmaj(row, cc)) = o;
}

// ---------------------------------------------------------------------------
// Pass 1: Z[n] += partial sum over one m-chunk of 2^(q'_n.k'_m); the
// 2nd-finishing wg of each (bh,rb) pair writes rinv = 1/Z for its 128 rows.
// wg = 256 thr (4 waves x 32 rows), streams 64 groups from L2, depth-4
// register pipeline, no barriers in the main loop.
// ---------------------------------------------------------------------------
__global__ __launch_bounds__(256, 6)
void mha_rowsumB(const char* __restrict__ qk, float* __restrict__ Z,
                 float* __restrict__ RI, int* __restrict__ TK)
{
    __shared__ int go;

    const int t = threadIdx.x, w = t >> 6, l = t & 63;
    const int wid = (blockIdx.x & 7) * 256 + (blockIdx.x >> 3);  // XCD swizzle
    const int bh = wid >> 5, r = wid & 31, rb = r & 15, mc = r >> 4;

    const char* Qp = qk + (size_t)bh * BHB;
    const char* Kp = qk + (size_t)BH_ * BHB + (size_t)bh * BHB;

    // Fixed A frags: rows rb*128 + w*32 + rg*16 + (l&15)
    bf16x8 af0_0, af0_1, af1_0, af1_1;
    {
        const char* g0 = Qp + rb * TILEB + (w * 2 + 0) * 2048;
        const char* g1 = Qp + rb * TILEB + (w * 2 + 1) * 2048;
        af0_0 = *(const bf16x8*)(g0 + l * 16);
        af0_1 = *(const bf16x8*)(g0 + 1024 + l * 16);
        af1_0 = *(const bf16x8*)(g1 + l * 16);
        af1_1 = *(const bf16x8*)(g1 + 1024 + l * 16);
    }

    float rs[2][4] = {};
    const char* pl = Kp + (size_t)mc * (NGC * 2048) + l * 16;

#define RS_COMP(B0, B1)                                                      \
    do {                                                                     \
        f32x4 ch0 = {0.f, 0.f, 0.f, 0.f};                                    \
        ch0 = __builtin_amdgcn_mfma_f32_16x16x32_bf16(af0_0, (B0), ch0, 0, 0, 0); \
        ch0 = __builtin_amdgcn_mfma_f32_16x16x32_bf16(af0_1, (B1), ch0, 0, 0, 0); \
        f32x4 ch1 = {0.f, 0.f, 0.f, 0.f};                                    \
        ch1 = __builtin_amdgcn_mfma_f32_16x16x32_bf16(af1_0, (B0), ch1, 0, 0, 0); \
        ch1 = __builtin_amdgcn_mfma_f32_16x16x32_bf16(af1_1, (B1), ch1, 0, 0, 0); \
        rs[0][0] += EXP2(ch0[0]); rs[0][1] += EXP2(ch0[1]);                  \
        rs[0][2] += EXP2(ch0[2]); rs[0][3] += EXP2(ch0[3]);                  \
        rs[1][0] += EXP2(ch1[0]); rs[1][1] += EXP2(ch1[1]);                  \
        rs[1][2] += EXP2(ch1[2]); rs[1][3] += EXP2(ch1[3]);                  \
    } while (0)

#define RS_LOAD(PA, PB, G) \
    do { PA = *(const bf16x8*)(pl + (size_t)(G) * 2048); \
         PB = *(const bf16x8*)(pl + (size_t)(G) * 2048 + 1024); } while (0)

    bf16x8 p0a, p0b, p1a, p1b, p2a, p2b, p3a, p3b;
    RS_LOAD(p0a, p0b, 0);
    RS_LOAD(p1a, p1b, 1);
    RS_LOAD(p2a, p2b, 2);
    RS_LOAD(p3a, p3b, 3);

    #pragma unroll 1
    for (int g = 0; g < NGC - 4; g += 4) {
        RS_COMP(p0a, p0b); RS_LOAD(p0a, p0b, g + 4);
        RS_COMP(p1a, p1b); RS_LOAD(p1a, p1b, g + 5);
        RS_COMP(p2a, p2b); RS_LOAD(p2a, p2b, g + 6);
        RS_COMP(p3a, p3b); RS_LOAD(p3a, p3b, g + 7);
    }
    RS_COMP(p0a, p0b);
    RS_COMP(p1a, p1b);
    RS_COMP(p2a, p2b);
    RS_COMP(p3a, p3b);
#undef RS_COMP
#undef RS_LOAD

    // Reduce across the 16 col-lanes; S-row = rg*16 + (l>>4)*4 + i
    #pragma unroll
    for (int rg = 0; rg < 2; ++rg)
        #pragma unroll
        for (int i = 0; i < 4; ++i) {
            rs[rg][i] += __shfl_xor(rs[rg][i], 1);
            rs[rg][i] += __shfl_xor(rs[rg][i], 2);
            rs[rg][i] += __shfl_xor(rs[rg][i], 4);
            rs[rg][i] += __shfl_xor(rs[rg][i], 8);
        }
    if ((l & 15) == 0) {
        #pragma unroll
        for (int rg = 0; rg < 2; ++rg) {
            const int rbase = bh * N_ + rb * PNL + w * 32 + rg * 16 + (l >> 4) * 4;
            #pragma unroll
            for (int i = 0; i < 4; ++i)
                atomicAdd(&Z[rbase + i], rs[rg][i]);
        }
    }
    __syncthreads();                                 // block's atomics issued
    __threadfence();                                 // release: Z visible
    if (t == 0) go = (atomicAdd(&TK[bh * 16 + rb], 1) == 1);
    __syncthreads();
    if (go) {                                        // 2nd wg: Z complete
        __threadfence();                             // acquire
        if (t < PNL) {
            const int idx = bh * N_ + rb * PNL + t;
            float z = __hip_atomic_load(&Z[idx], __ATOMIC_RELAXED,
                                        __HIP_MEMORY_SCOPE_AGENT);
            RI[idx] = 1.0f / z;
        }
    }
}

// ---------------------------------------------------------------------------
// Pass 2: CS[m] += partial sum over one n-chunk of 2^(q'_n.k'_m)*rinv[n];
// 2nd-finishing wg of each (bh,cb) pair writes out = CS[m] * v[m,:].
// ---------------------------------------------------------------------------
__global__ __launch_bounds__(256, 6)
void mha_colsumB(const char* __restrict__ qk, const float* __restrict__ RI,
                 float* __restrict__ CS, int* __restrict__ TK,
                 const float* __restrict__ v, float* __restrict__ out)
{
    __shared__ float lcs[PNL];
    __shared__ int go;

    const int t = threadIdx.x, w = t >> 6, l = t & 63;
    const int wid = (blockIdx.x & 7) * 256 + (blockIdx.x >> 3);
    const int bh = wid >> 5, r = wid & 31, cb = r & 15, nc = r >> 4;

    const char* Qp = qk + (size_t)bh * BHB;
    const char* Kp = qk + (size_t)BH_ * BHB + (size_t)bh * BHB;

    // Fixed B frags: cols cb*128 + w*32 + rg*16 + (l&15)
    bf16x8 kf0_0, kf0_1, kf1_0, kf1_1;
    {
        const char* g0 = Kp + cb * TILEB + (w * 2 + 0) * 2048;
        const char* g1 = Kp + cb * TILEB + (w * 2 + 1) * 2048;
        kf0_0 = *(const bf16x8*)(g0 + l * 16);
        kf0_1 = *(const bf16x8*)(g0 + 1024 + l * 16);
        kf1_0 = *(const bf16x8*)(g1 + l * 16);
        kf1_1 = *(const bf16x8*)(g1 + 1024 + l * 16);
    }

    float ca0 = 0.f, ca1 = 0.f;
    const char* pl = Qp + (size_t)nc * (NGC * 2048) + l * 16;
    const float* Rl = RI + (size_t)bh * N_ + nc * (NGC * 16) + (l >> 4) * 4;

#define CS_COMP(A0, A1, R4)                                                  \
    do {                                                                     \
        f32x4 ch0 = {0.f, 0.f, 0.f, 0.f};                                    \
        ch0 = __builtin_amdgcn_mfma_f32_16x16x32_bf16((A0), kf0_0, ch0, 0, 0, 0); \
        ch0 = __builtin_amdgcn_mfma_f32_16x16x32_bf16((A1), kf0_1, ch0, 0, 0, 0); \
        f32x4 ch1 = {0.f, 0.f, 0.f, 0.f};                                    \
        ch1 = __builtin_amdgcn_mfma_f32_16x16x32_bf16((A0), kf1_0, ch1, 0, 0, 0); \
        ch1 = __builtin_amdgcn_mfma_f32_16x16x32_bf16((A1), kf1_1, ch1, 0, 0, 0); \
        ca0 += EXP2(ch0[0]) * (R4).x + EXP2(ch0[1]) * (R4).y                 \
             + EXP2(ch0[2]) * (R4).z + EXP2(ch0[3]) * (R4).w;                \
        ca1 += EXP2(ch1[0]) * (R4).x + EXP2(ch1[1]) * (R4).y                 \
             + EXP2(ch1[2]) * (R4).z + EXP2(ch1[3]) * (R4).w;                \
    } while (0)

#define CS_LOAD(PA, PB, PR, G) \
    do { PA = *(const bf16x8*)(pl + (size_t)(G) * 2048);          \
         PB = *(const bf16x8*)(pl + (size_t)(G) * 2048 + 1024);   \
         PR = *(const float4*)(Rl + (G) * 16); } while (0)

    bf16x8 p0a, p0b, p1a, p1b, p2a, p2b, p3a, p3b;
    float4 r0, r1, r2, r3;
    CS_LOAD(p0a, p0b, r0, 0);
    CS_LOAD(p1a, p1b, r1, 1);
    CS_LOAD(p2a, p2b, r2, 2);
    CS_LOAD(p3a, p3b, r3, 3);

    #pragma unroll 1
    for (int g = 0; g < NGC - 4; g += 4) {
        CS_COMP(p0a, p0b, r0); CS_LOAD(p0a, p0b, r0, g + 4);
        CS_COMP(p1a, p1b, r1); CS_LOAD(p1a, p1b, r1, g + 5);
        CS_COMP(p2a, p2b, r2); CS_LOAD(p2a, p2b, r2, g + 6);
        CS_COMP(p3a, p3b, r3); CS_LOAD(p3a, p3b, r3, g + 7);
    }
    CS_COMP(p0a, p0b, r0);
    CS_COMP(p1a, p1b, r1);
    CS_COMP(p2a, p2b, r2);
    CS_COMP(p3a, p3b, r3);
#undef CS_COMP
#undef CS_LOAD

    // Butterfly over the 4 row-groups -> lanes 0..15 hold colsum partials
    ca0 += __shfl_xor(ca0, 16); ca0 += __shfl_xor(ca0, 32);
    ca1 += __shfl_xor(ca1, 16); ca1 += __shfl_xor(ca1, 32);
    if (l < 16) {
        atomicAdd(&CS[bh * N_ + cb * PNL + w * 32 + l],      ca0);
        atomicAdd(&CS[bh * N_ + cb * PNL + w * 32 + 16 + l], ca1);
    }
    __syncthreads();
    __threadfence();                                 // release: CS visible
    if (t == 0) go = (atomicAdd(&TK[1024 + bh * 16 + cb], 1) == 1);
    __syncthreads();
    if (go) {                                        // 2nd wg: CS complete
        __threadfence();                             // acquire
        if (t < PNL)
            lcs[t] = __hip_atomic_load(&CS[bh * N_ + cb * PNL + t],
                                       __ATOMIC_RELAXED, __HIP_MEMORY_SCOPE_AGENT);
        __syncthreads();
        const float4* Vg = (const float4*)(v + ((size_t)bh * N_ + cb * PNL) * D_);
        float4* Og = (float4*)(out + ((size_t)bh * N_ + cb * PNL) * D_);
        #pragma unroll
        for (int i = 0; i < 8; ++i) {
            int id = i * 256 + t;                    // 2048 float4 units
            float s = lcs[id >> 4];
            float4 vv = Vg[id];
            float4 o; o.x = vv.x * s; o.y = vv.y * s; o.z = vv.z * s; o.w = vv.w * s;
            Og[id] = o;
        }
    }
}

// ===========================================================================
// Fallback (R2 path) if ws_size is too small for the bf16 staging buffers.
// ===========================================================================
#define FTS 128
#define FNT 16

__device__ __forceinline__ bf16x8 cvt8(const float* p) {
    float4 a = *(const float4*)p;
    float4 b = *(const float4*)(p + 4);
    bf16x8 r;
    r[0] = f2bf(a.x); r[1] = f2bf(a.y); r[2] = f2bf(a.z); r[3] = f2bf(a.w);
    r[4] = f2bf(b.x); r[5] = f2bf(b.y); r[6] = f2bf(b.z); r[7] = f2bf(b.w);
    return r;
}
__device__ __forceinline__ void fstage(char* lds, const float* src, int t) {
    #pragma unroll
    for (int i = 0; i < 2; ++i) {
        int ch = i * 512 + t, r = ch >> 3, cc = ch & 7;
        bf16x8 v = cvt8(src + (size_t)r * D_ + cc * 8);
        *(bf16x8*)(lds + r * 128 + ((cc ^ (r & 7)) << 4)) = v;
    }
}
__device__ __forceinline__ bf16x8 fread(const char* lds, int row, int cc) {
    return *(const bf16x8*)(lds + row * 128 + ((cc ^ (row & 7)) << 4));
}

__global__ __launch_bounds__(512)
void mha_rowsum_fb(const float* __restrict__ q, const float* __restrict__ k,
                   float* __restrict__ rinv)
{
    __shared__ __align__(16) char KT[FTS * 128];
    const int t = threadIdx.x, w = t >> 6, l = t & 63;
    const int bh = blockIdx.x / FNT, rb = blockIdx.x % FNT;
    const float* Qg = q + (size_t)bh * N_ * D_;
    const float* Kg = k + (size_t)bh * N_ * D_;
    const int qrow = rb * FTS + w * 16 + (l & 15);
    bf16x8 af[2];
    #pragma unroll
    for (int kh = 0; kh < 2; ++kh)
        af[kh] = cvt8(Qg + (size_t)qrow * D_ + kh * 32 + (l >> 4) * 8);
    float rs[4] = {0.f, 0.f, 0.f, 0.f};
    for (int ct = 0; ct < FNT; ++ct) {
        __syncthreads();
        fstage(KT, Kg + (size_t)ct * FTS * D_, t);
        __syncthreads();
        #pragma unroll
        for (int cj = 0; cj < 8; ++cj) {
            const int krow = cj * 16 + (l & 15);
            f32x4 c = {0.f, 0.f, 0.f, 0.f};
            #pragma unroll
            for (int kh = 0; kh < 2; ++kh)
                c = __builtin_amdgcn_mfma_f32_16x16x32_bf16(af[kh], fread(KT, krow, kh * 4 + (l >> 4)), c, 0, 0, 0);
            rs[0] += __expf(c[0] * SCALE); rs[1] += __expf(c[1] * SCALE);
            rs[2] += __expf(c[2] * SCALE); rs[3] += __expf(c[3] * SCALE);
        }
    }
    #pragma unroll
    for (int i = 0; i < 4; ++i) {
        rs[i] += __shfl_xor(rs[i], 1); rs[i] += __shfl_xor(rs[i], 2);
        rs[i] += __shfl_xor(rs[i], 4); rs[i] += __shfl_xor(rs[i], 8);
    }
    if ((l & 15) == 0) {
        const int rbase = rb * FTS + w * 16 + (l >> 4) * 4;
        #pragma unroll
        for (int i = 0; i < 4; ++i)
            rinv[(size_t)bh * N_ + rbase + i] = 1.0f / rs[i];
    }
}

__global__ __launch_bounds__(512)
void mha_colsum_fb(const float* __restrict__ q, const float* __restrict__ k,
                   const float* __restrict__ v, const float* __restrict__ rinv,
                   float* __restrict__ out)
{
    __shared__ __align__(16) char QT[FTS * 128];
    __shared__ float rv[FTS];
    __shared__ float cs2[FTS];
    const int t = threadIdx.x, w = t >> 6, l = t & 63;
    const int bh = blockIdx.x / FNT, cb = blockIdx.x % FNT;
    const float* Qg = q + (size_t)bh * N_ * D_;
    const float* Kg = k + (size_t)bh * N_ * D_;
    const float* Rg = rinv + (size_t)bh * N_;
    const int kcol = cb * FTS + w * 16 + (l & 15);
    bf16x8 kf[2];
    #pragma unroll
    for (int kh = 0; kh < 2; ++kh)
        kf[kh] = cvt8(Kg + (size_t)kcol * D_ + kh * 32 + (l >> 4) * 8);
    float ca = 0.f;
    for (int rt = 0; rt < FNT; ++rt) {
        __syncthreads();
        fstage(QT, Qg + (size_t)rt * FTS * D_, t);
        if (t < FTS) rv[t] = Rg[rt * FTS + t];
        __syncthreads();
        #pragma unroll
        for (int rj = 0; rj < 8; ++rj) {
            const int qr = rj * 16 + (l & 15);
            f32x4 c = {0.f, 0.f, 0.f, 0.f};
            #pragma unroll
            for (int kh = 0; kh < 2; ++kh)
                c = __builtin_amdgcn_mfma_f32_16x16x32_bf16(fread(QT, qr, kh * 4 + (l >> 4)), kf[kh], c, 0, 0, 0);
            float4 r4 = *(const float4*)&rv[rj * 16 + (l >> 4) * 4];
            ca += __expf(c[0] * SCALE) * r4.x + __expf(c[1] * SCALE) * r4.y
                + __expf(c[2] * SCALE) * r4.z + __expf(c[3] * SCALE) * r4.w;
        }
    }
    ca += __shfl_xor(ca, 16); ca += __shfl_xor(ca, 32);
    if (l < 16) cs2[w * 16 + l] = ca;
    __syncthreads();
    const float4* Vg = (const float4*)(v + (size_t)bh * N_ * D_ + (size_t)cb * FTS * D_);
    float4* Og = (float4*)(out + (size_t)bh * N_ * D_ + (size_t)cb * FTS * D_);
    #pragma unroll
    for (int i = 0; i < 4; ++i) {
        int id = i * 512 + t;
        float s = cs2[id >> 4];
        float4 vv = Vg[id];
        float4 o; o.x = vv.x * s; o.y = vv.y * s; o.z = vv.z * s; o.w = vv.w * s;
        Og[id] = o;
    }
}

// ---------------------------------------------------------------------------
extern "C" void kernel_launch(void* const* d_in, const int* in_sizes, int n_in,
                              void* d_out, int out_size, void* d_ws, size_t ws_size,
                              hipStream_t stream)
{
    const float* q = (const float*)d_in[0];
    const float* k = (const float*)d_in[1];
    const float* v = (const float*)d_in[2];
    float* out = (float*)d_out;

    // ws layout: qk image (32M) | Z (512K) | CS (512K) | TK (16K) | RI (512K)
    const size_t need = QKB + (size_t)NZW * 4 * 3 + 16384;

    if (ws_size >= need) {
        char*  qk = (char*)d_ws;
        float* Z  = (float*)(qk + QKB);
        float* CS = Z + NZW;
        int*   TK = (int*)(CS + NZW);
        float* RI = (float*)((char*)TK + 16384);
        mha_convert<<<dim3(2 * BH_ * N_ * 8 / 512), dim3(512), 0, stream>>>(q, k, qk);
        mha_rowsumB<<<dim3(2048), dim3(256), 0, stream>>>(qk, Z, RI, TK);
        mha_colsumB<<<dim3(2048), dim3(256), 0, stream>>>(qk, RI, CS, TK, v, out);
    } else {
        float* rinv = (float*)d_ws;
        mha_rowsum_fb<<<dim3(BH_ * FNT), dim3(512), 0, stream>>>(q, k, rinv);
        mha_colsum_fb<<<dim3(BH_ * FNT), dim3(512), 0, stream>>>(q, k, v, rinv, out);
    }
}